// Round 3
// baseline (153.262 us; speedup 1.0000x reference)
//
#include <hip/hip_runtime.h>
#include <hip/hip_bf16.h>
#include <math.h>
#include <stdint.h>

#define B_    2
#define S_    2048
#define HID_  768
#define NH_   12
#define HD_   64
#define NROWS (B_ * S_)                    // 4096
#define N_HID_ELEM (NROWS * HID_)          // 3145728
#define N_W_ELEM   (HID_ * HID_)           // 589824

// attention LDS geometry: 224 staged keys, row stride 232
#define KW   224
#define KSTR 232

typedef __bf16 bf16x8 __attribute__((ext_vector_type(8)));
typedef float  floatx4 __attribute__((ext_vector_type(4)));

__device__ __forceinline__ void cvt_write8(const float4& x, const float4& y,
                                           __hip_bfloat16* d)
{
    __hip_bfloat16 t[8] = { __float2bfloat16(x.x), __float2bfloat16(x.y),
                            __float2bfloat16(x.z), __float2bfloat16(x.w),
                            __float2bfloat16(y.x), __float2bfloat16(y.y),
                            __float2bfloat16(y.z), __float2bfloat16(y.w) };
    *reinterpret_cast<bf16x8*>(d) = *reinterpret_cast<bf16x8*>(t);
}

// ---------------------------------------------------------------------------
// Fused 64x64-tile GEMM: C = A @ W^T, K=768, intra-block split-K(2).
// W is ALWAYS fp32 (converted in-register).  AF32: A fp32 too (gemm1 reads
// the raw hidden states -> no separate convert kernel, no bf16 round-trip).
// Reg-staging (global->reg->cvt->ds_write) with T14 placement: loads issued
// right AFTER the per-iter barrier, consumed by cvt+ds_write AFTER compute ->
// the barrier's implicit vmcnt(0) drain finds nothing outstanding and the
// load latency hides under the MFMA phase.  One __syncthreads per K-step.
// LDS dest linear / global source pre-swizzled, read swizzled (rule #21),
// so fragment ds_read_b128 stays 2-way (free).
// ROPE=1: computes its own cos/sin table in LDS (4 sincosf/thread, hidden
// under the tile-0 load) and writes Q,Qr bf16.  ROPE=0: writes fp32 Cf.
// XCD-chunked block remap: 768 blocks = 8 XCDs x 96; each XCD covers 8
// m-panels x all 12 n-blocks -> A+W working set ~3.8 MB fits its 4 MB L2.
// ---------------------------------------------------------------------------
template<int ROPE, int AF32>
__global__ __launch_bounds__(512, 4) void gemm64f(
    const void*  __restrict__ Asrc,
    const float* __restrict__ Wf,
    __hip_bfloat16* __restrict__ C,        // ROPE: Q
    __hip_bfloat16* __restrict__ C2,       // ROPE: Qr
    float* __restrict__ Cf,                // !ROPE
    const int* __restrict__ pos_idx)
{
    constexpr int K = HID_;
    // [kg][buf][half][row][32]  (row stride 64B; dest kept LINEAR)
    __shared__ __align__(16) __hip_bfloat16 Ald[2][2][2][64][32];  // 32 KB
    __shared__ __align__(16) __hip_bfloat16 Wld[2][2][2][64][32];  // 32 KB
    __shared__ float2 Rt[64 * 32];                                 // 16 KB (ROPE)

    const int tid  = threadIdx.x;
    const int kg   = tid >> 8;             // k-group 0/1
    const int wv4  = (tid >> 6) & 3;       // wave within group
    const int lane = tid & 63;
    const int l16  = lane & 15;
    const int quad = lane >> 4;

    // XCD-chunked bijective remap (768 = 8 * 96), n-major original order
    const int lin = blockIdx.x + 12 * blockIdx.y;      // grid (12, 64)
    const int o   = (lin & 7) * 96 + (lin >> 3);
    const int m0  = (o / 12) * 64;
    const int n0  = (o % 12) * 64;

    // staging geometry: chunk c in [0,256) per kg: row=c>>2, slot=c&3.
    const int c    = wv4 * 64 + lane;
    const int sr   = c >> 2;
    const int slot = c & 3;
    const int sws  = slot ^ ((sr >> 1) & 3);           // pre-swizzled source granule
    const int kb   = kg * 384;

    const float* pWf = Wf + (size_t)(n0 + sr) * K + kb + sws * 8;
    const float* pAf = (const float*)Asrc + (size_t)(m0 + sr) * K + kb + sws * 8;
    const __hip_bfloat16* pAb = (const __hip_bfloat16*)Asrc
                                + (size_t)(m0 + sr) * K + kb + sws * 8;

    // LDS dest (linear lane order, matches what global_load_lds would write)
    const int dr = wv4 * 16 + (lane >> 2);
    const int dc = (lane & 3) * 8;

    floatx4 acc[4] = {};
    const int ra  = wv4 * 16 + l16;                    // A-fragment row
    const int qsw = (quad ^ ((l16 >> 1) & 3)) * 8;     // swizzled read granule

    float4 rA[2][2];   // [half][part]  (AF32)
    uint4  rAb[2];     // [half]        (!AF32, 8 bf16 each)
    float4 rW[2][2];

#define LOADR(itx) do {                                                        \
        const int ko_ = (itx) * 64;                                            \
        if constexpr (AF32) {                                                  \
            rA[0][0] = *(const float4*)(pAf + ko_);                            \
            rA[0][1] = *(const float4*)(pAf + ko_ + 4);                        \
            rA[1][0] = *(const float4*)(pAf + ko_ + 32);                       \
            rA[1][1] = *(const float4*)(pAf + ko_ + 36);                       \
        } else {                                                               \
            rAb[0] = *(const uint4*)(pAb + ko_);                               \
            rAb[1] = *(const uint4*)(pAb + ko_ + 32);                          \
        }                                                                      \
        rW[0][0] = *(const float4*)(pWf + ko_);                                \
        rW[0][1] = *(const float4*)(pWf + ko_ + 4);                            \
        rW[1][0] = *(const float4*)(pWf + ko_ + 32);                           \
        rW[1][1] = *(const float4*)(pWf + ko_ + 36);                           \
    } while (0)

#define WRITES(buf) do {                                                       \
        if constexpr (AF32) {                                                  \
            cvt_write8(rA[0][0], rA[0][1], &Ald[kg][buf][0][dr][dc]);          \
            cvt_write8(rA[1][0], rA[1][1], &Ald[kg][buf][1][dr][dc]);          \
        } else {                                                               \
            *reinterpret_cast<uint4*>(&Ald[kg][buf][0][dr][dc]) = rAb[0];      \
            *reinterpret_cast<uint4*>(&Ald[kg][buf][1][dr][dc]) = rAb[1];      \
        }                                                                      \
        cvt_write8(rW[0][0], rW[0][1], &Wld[kg][buf][0][dr][dc]);              \
        cvt_write8(rW[1][0], rW[1][1], &Wld[kg][buf][1][dr][dc]);              \
    } while (0)

    // prologue: tile-0 loads in flight while (ROPE) the trig table computes
    LOADR(0);
    if constexpr (ROPE) {
        for (int t = tid; t < 64 * 32; t += 512) {
            int rr = t >> 5, f = t & 31;
            int s = (m0 + rr) & (S_ - 1);
            float inv = exp2f((float)f * (-0.41524101186092024f)); // -log2(1e4)/32
            float sn, cs;
            sincosf((float)pos_idx[s] * inv, &sn, &cs);
            Rt[t] = make_float2(cs, sn);
        }
    }
    WRITES(0);

#pragma unroll
    for (int it = 0; it < 6; ++it) {
        const int cur = it & 1;
        __syncthreads();                   // buf[cur] writes visible; no vm outstanding
        if (it + 1 < 6) LOADR(it + 1);     // issue early; consumed after compute (T14)
#pragma unroll
        for (int ks = 0; ks < 2; ++ks) {
            bf16x8 a = *reinterpret_cast<const bf16x8*>(&Ald[kg][cur][ks][ra][qsw]);
#pragma unroll
            for (int u = 0; u < 4; ++u) {
                bf16x8 w = *reinterpret_cast<const bf16x8*>(
                    &Wld[kg][cur][ks][u * 16 + l16][qsw]);
                acc[u] = __builtin_amdgcn_mfma_f32_16x16x32_bf16(a, w, acc[u], 0, 0, 0);
            }
        }
        if (it + 1 < 6) WRITES(cur ^ 1);   // waits its loads here (latency hidden)
    }
#undef LOADR
#undef WRITES

    // ---- cross-group reduction through LDS (reuse Ald region: 64x68 f32) ----
    __syncthreads();
    float* Red = reinterpret_cast<float*>(&Ald[0][0][0][0][0]);   // 17.4 KB < 32 KB
    if (kg == 1) {
#pragma unroll
        for (int u = 0; u < 4; ++u)
#pragma unroll
            for (int r = 0; r < 4; ++r)
                Red[(wv4 * 16 + quad * 4 + r) * 68 + u * 16 + l16] = acc[u][r];
    }
    __syncthreads();
    if (kg == 1) return;
#pragma unroll
    for (int u = 0; u < 4; ++u)
#pragma unroll
        for (int r = 0; r < 4; ++r)
            acc[u][r] += Red[(wv4 * 16 + quad * 4 + r) * 68 + u * 16 + l16];

    // ---- epilogue (kg0 only): D row = wv4*16+quad*4+r, col = n0+u*16+l16 ----
    if constexpr (ROPE) {
#pragma unroll
        for (int r = 0; r < 4; ++r) {
            int tr = wv4 * 16 + quad * 4 + r;
            int m  = m0 + tr;
#pragma unroll
            for (int u = 0; u < 2; ++u) {
                float2 cssn = Rt[tr * 32 + u * 16 + l16];
                float cs = cssn.x, sn = cssn.y;
                float q0 = acc[u][r];
                float q1 = acc[u + 2][r];
                size_t base = (size_t)m * HID_ + n0 + u * 16 + l16;
                C [base]      = __float2bfloat16(q0);
                C [base + 32] = __float2bfloat16(q1);
                C2[base]      = __float2bfloat16(q0 * cs - q1 * sn);
                C2[base + 32] = __float2bfloat16(q1 * cs + q0 * sn);
            }
        }
    } else {
#pragma unroll
        for (int u = 0; u < 4; ++u)
#pragma unroll
            for (int r = 0; r < 4; ++r) {
                int row = m0 + wv4 * 16 + quad * 4 + r;
                int col = n0 + u * 16 + l16;
                Cf[(size_t)row * HID_ + col] = acc[u][r];
            }
    }
}

// ---------------------------------------------------------------------------
// Banded attention; conflict-free Vt staging + LDS-repacked O writeback.
// (KSTR=232 -> row stride 464B -> bank advance 20 mod 32 -> period-8 spread:
//  fragment reads are 2-way max = free; staging writes lane-consecutive = free.)
// ---------------------------------------------------------------------------
__global__ __launch_bounds__(256) void attn_kernel(
    const __hip_bfloat16* __restrict__ Q,    // pre-rope  (= V)
    const __hip_bfloat16* __restrict__ Qr,   // post-rope (= Q = K)
    __hip_bfloat16* __restrict__ O)
{
    __shared__ __align__(16) __hip_bfloat16 Vt[64][KSTR];   // [dim][window]
    __shared__ __align__(16) __hip_bfloat16 Pl[64][KSTR];   // [row][window]

    const int bh = blockIdx.y;
    const int b  = bh / NH_;
    const int h  = bh % NH_;
    const int i0 = blockIdx.x * 64;
    const int tid = threadIdx.x;

    // stage V^T: one key row per lane (banks = tid/2 -> 2-way = free).
    if (tid < KW) {
        int j  = i0 - 64 + tid;
        int jc = min(max(j, 0), S_ - 1);
        const __hip_bfloat16* vrow = Q + ((size_t)(b * S_ + jc)) * HID_ + h * HD_;
#pragma unroll
        for (int d8i = 0; d8i < 8; ++d8i) {
            bf16x8 v = *reinterpret_cast<const bf16x8*>(vrow + d8i * 8);
            const __hip_bfloat16* ve = reinterpret_cast<const __hip_bfloat16*>(&v);
#pragma unroll
            for (int e = 0; e < 8; ++e) Vt[d8i * 8 + e][tid] = ve[e];
        }
    }
    __syncthreads();

    const int wv   = tid >> 6;
    const int lane = tid & 63;
    const int l16  = lane & 15;
    const int quad = lane >> 4;

    // ---- QK^T over the 10 tiles intersecting this wave's band ----
    floatx4 sc[10] = {};
    const __hip_bfloat16* qrow =
        Qr + ((size_t)(b * S_ + i0 + wv * 16 + l16)) * HID_ + h * HD_ + quad * 8;
#pragma unroll
    for (int ks = 0; ks < 2; ++ks) {
        bf16x8 a = *reinterpret_cast<const bf16x8*>(qrow + ks * 32);
#pragma unroll
        for (int t = 0; t < 10; ++t) {
            int j = i0 - 64 + (wv + t) * 16 + l16;
            int jc = min(max(j, 0), S_ - 1);
            bf16x8 bfr = *reinterpret_cast<const bf16x8*>(
                Qr + ((size_t)(b * S_ + jc)) * HID_ + h * HD_ + ks * 32 + quad * 8);
            sc[t] = __builtin_amdgcn_mfma_f32_16x16x32_bf16(a, bfr, sc[t], 0, 0, 0);
        }
    }

    // ---- masked softmax per row ----
    const float scale = 0.125f;
    float denom[4];
#pragma unroll
    for (int r = 0; r < 4; ++r) {
        const int R = wv * 16 + quad * 4 + r;
        float xv[10];
        float mx = -3.0e38f;
#pragma unroll
        for (int t = 0; t < 10; ++t) {
            int w = (wv + t) * 16 + l16;
            int j = i0 - 64 + w;
            bool valid = (w >= R) && (w <= R + 128) && (j >= 0) && (j < S_);
            float x = valid ? sc[t][r] * scale : -1.0e30f;
            xv[t] = x;
            mx = fmaxf(mx, x);
        }
#pragma unroll
        for (int msk = 1; msk < 16; msk <<= 1) mx = fmaxf(mx, __shfl_xor(mx, msk, 64));
        float sum = 0.f;
#pragma unroll
        for (int t = 0; t < 10; ++t) {
            float p = __expf(xv[t] - mx);
            sum += p;
            Pl[R][(wv + t) * 16 + l16] = __float2bfloat16(p);
        }
#pragma unroll
        for (int msk = 1; msk < 16; msk <<= 1) sum += __shfl_xor(sum, msk, 64);
        denom[r] = sum;
    }
    __syncthreads();

    // ---- PV over the wave's 160-wide band ----
    floatx4 oacc[4] = {};
#pragma unroll
    for (int c = 0; c < 5; ++c) {
        const int base = wv * 16 + c * 32;
        bf16x8 a = *reinterpret_cast<const bf16x8*>(&Pl[wv * 16 + l16][base + quad * 8]);
#pragma unroll
        for (int u = 0; u < 4; ++u) {
            bf16x8 bfr = *reinterpret_cast<const bf16x8*>(&Vt[u * 16 + l16][base + quad * 8]);
            oacc[u] = __builtin_amdgcn_mfma_f32_16x16x32_bf16(a, bfr, oacc[u], 0, 0, 0);
        }
    }

    // ---- O writeback via LDS repack (reuse Pl as f32 [64][68]) ----
    __syncthreads();                       // all Pl/Vt reads done
    float* Of = reinterpret_cast<float*>(&Pl[0][0]);
#pragma unroll
    for (int u = 0; u < 4; ++u)
#pragma unroll
        for (int r = 0; r < 4; ++r)
            Of[(wv * 16 + quad * 4 + r) * 68 + u * 16 + l16] = oacc[u][r] / denom[r];
    __syncthreads();
    {
        int row = tid >> 2;
        int seg = (tid & 3) * 16;
        __hip_bfloat16 ob[16];
#pragma unroll
        for (int e = 0; e < 16; ++e)
            ob[e] = __float2bfloat16(Of[row * 68 + seg + e]);
        __hip_bfloat16* dst = O + ((size_t)(b * S_ + i0 + row)) * HID_ + h * HD_ + seg;
        *reinterpret_cast<bf16x8*>(dst)     = *reinterpret_cast<bf16x8*>(ob);
        *reinterpret_cast<bf16x8*>(dst + 8) = *reinterpret_cast<bf16x8*>(ob + 8);
    }
}

// ---------------------------------------------------------------------------
extern "C" void kernel_launch(void* const* d_in, const int* in_sizes, int n_in,
                              void* d_out, int out_size, void* d_ws, size_t ws_size,
                              hipStream_t stream)
{
    int ih = -1, iw1 = -1, iw2 = -1, ip = -1;
    for (int i = 0; i < n_in; ++i) {
        int s = in_sizes[i];
        if      (s == N_HID_ELEM && ih < 0) ih = i;
        else if (s == N_W_ELEM)  { if (iw1 < 0) iw1 = i; else if (iw2 < 0) iw2 = i; }
        else if (s == S_ && ip < 0) ip = i;
    }
    if (ih < 0)  ih = 0;
    if (iw1 < 0) iw1 = 1;
    if (iw2 < 0) iw2 = 2;
    if (ip < 0)  ip = 5;

    const float* hidden = (const float*)d_in[ih];
    const float* w1     = (const float*)d_in[iw1];   // Wq
    const float* w2     = (const float*)d_in[iw2];   // Wo
    const int*   pos    = (const int*)d_in[ip];

    __hip_bfloat16* Q  = (__hip_bfloat16*)d_ws;
    __hip_bfloat16* Qr = Q  + N_HID_ELEM;
    __hip_bfloat16* AO = Qr + N_HID_ELEM;

    dim3 gblk(HID_ / 64, NROWS / 64);   // (12, 64) = 768 blocks, n-major linear

    // GEMM1 (fp32 A, fp32 W, in-register convert) + fused RoPE -> Q, Qr
    gemm64f<1, 1><<<gblk, 512, 0, stream>>>(hidden, w1, Q, Qr, nullptr, pos);

    attn_kernel<<<dim3(S_ / 64, B_ * NH_), 256, 0, stream>>>(Q, Qr, AO);

    // GEMM2 (bf16 A from attn, fp32 W) -> fp32 out
    gemm64f<0, 0><<<gblk, 512, 0, stream>>>(AO, w2, nullptr, nullptr, (float*)d_out,
                                            nullptr);
}

// Round 4
// 137.886 us; speedup vs baseline: 1.1115x; 1.1115x over previous
//
#include <hip/hip_runtime.h>
#include <hip/hip_bf16.h>
#include <math.h>
#include <stdint.h>

#define B_    2
#define S_    2048
#define HID_  768
#define NH_   12
#define HD_   64
#define NROWS (B_ * S_)                    // 4096
#define N_HID_ELEM (NROWS * HID_)          // 3145728
#define N_W_ELEM   (HID_ * HID_)           // 589824

// attention LDS geometry: 224 staged keys, row stride 232
#define KW   224
#define KSTR 232

// RoPE table: [S][32] float2 (cos, sin)
#define TAB_ELEMS (S_ * 32)

typedef __bf16 bf16x8 __attribute__((ext_vector_type(8)));
typedef float  floatx4 __attribute__((ext_vector_type(4)));

// fp32 -> bf16 conversion of hidden + Wq + Wo (x4 vectorized) + RoPE cos/sin table
__global__ void convert_inputs_kernel(const float* __restrict__ src_hidden,
                                      const float* __restrict__ src_w1,
                                      const float* __restrict__ src_w2,
                                      const int*   __restrict__ pos_idx,
                                      __hip_bfloat16* __restrict__ Hb,
                                      __hip_bfloat16* __restrict__ Wqb,
                                      __hip_bfloat16* __restrict__ Wob,
                                      float2* __restrict__ tab)
{
    int i = blockIdx.x * blockDim.x + threadIdx.x;   // float4 index
    const int NH4 = N_HID_ELEM / 4, NW4 = N_W_ELEM / 4;
    const int total4 = NH4 + 2 * NW4;
    if (i < total4) {
        const float* src;
        __hip_bfloat16* dst;
        int off;
        if (i < NH4)           { src = src_hidden; dst = Hb;  off = i; }
        else if (i < NH4+NW4)  { src = src_w1;     dst = Wqb; off = i - NH4; }
        else                   { src = src_w2;     dst = Wob; off = i - NH4 - NW4; }
        float4 v = reinterpret_cast<const float4*>(src)[off];
        __hip_bfloat16 o[4] = { __float2bfloat16(v.x), __float2bfloat16(v.y),
                                __float2bfloat16(v.z), __float2bfloat16(v.w) };
        *reinterpret_cast<uint64_t*>(dst + 4 * (size_t)off) = *reinterpret_cast<uint64_t*>(o);
    } else {
        int t = i - total4;
        if (t < TAB_ELEMS) {
            int s = t >> 5, f = t & 31;
            float inv = exp2f((float)f * (-0.41524101186092024f)); // -log2(1e4)/32
            float sn, cs;
            sincosf((float)pos_idx[s] * inv, &sn, &cs);
            tab[t] = make_float2(cs, sn);
        }
    }
}

__device__ __forceinline__ void gload_lds16(const __hip_bfloat16* g, __hip_bfloat16* l)
{
    __builtin_amdgcn_global_load_lds(
        (const __attribute__((address_space(1))) void*)g,
        (__attribute__((address_space(3))) void*)l, 16, 0, 0);
}

// ---------------------------------------------------------------------------
// 64x64-tile GEMM, intra-block split-K(2), depth-2 prefetch with COUNTED vmcnt,
// and XOR-swizzled LDS k-granules (round-2 proven structure; glds staging).
// ---------------------------------------------------------------------------
template<int ROPE>
__global__ __launch_bounds__(512) void gemm64k2(
    const __hip_bfloat16* __restrict__ A,
    const __hip_bfloat16* __restrict__ W,
    __hip_bfloat16* __restrict__ C,        // ROPE: Q
    __hip_bfloat16* __restrict__ C2,       // ROPE: Qr
    float* __restrict__ Cf,                // !ROPE
    const float2* __restrict__ tab,
    int M, int N, int K)
{
    // [kg][buf][half][row][32]  (row stride 64B; LDS kept LINEAR for glds)
    __shared__ __align__(16) __hip_bfloat16 Ald[2][2][2][64][32];  // 32 KB
    __shared__ __align__(16) __hip_bfloat16 Wld[2][2][2][64][32];  // 32 KB

    const int tid  = threadIdx.x;
    const int kg   = tid >> 8;             // k-group 0/1
    const int wv4  = (tid >> 6) & 3;       // wave within group
    const int lane = tid & 63;
    const int l16  = lane & 15;
    const int quad = lane >> 4;
    const int m0 = blockIdx.x * 64;
    const int n0 = blockIdx.y * 64;

    // staging geometry within group: chunk c in [0,256): row=c>>2, slot=c&3.
    // Physical slot receives logical k-granule  slot ^ ((row>>1)&3).
    const int c    = wv4 * 64 + lane;
    const int sr   = c >> 2;
    const int sc8  = ((c & 3) ^ ((sr >> 1) & 3)) * 8;   // pre-swizzled global k-offset
    const int kbase = kg * 384;

    const __hip_bfloat16* gA = A + (size_t)(m0 + sr) * K + kbase + sc8;
    const __hip_bfloat16* gW = W + (size_t)(n0 + sr) * K + kbase + sc8;

    floatx4 acc[4] = {};
    const int ra  = wv4 * 16 + l16;                      // A-fragment row for this lane
    const int qsw = (quad ^ ((l16 >> 1) & 3)) * 8;       // swizzled read granule (elems)

#define STAGE(itx, buf) do {                                          \
        const int ko_ = (itx) * 64;                                   \
        gload_lds16(gA + ko_,      &Ald[kg][buf][0][wv4 * 16][0]);    \
        gload_lds16(gA + ko_ + 32, &Ald[kg][buf][1][wv4 * 16][0]);    \
        gload_lds16(gW + ko_,      &Wld[kg][buf][0][wv4 * 16][0]);    \
        gload_lds16(gW + ko_ + 32, &Wld[kg][buf][1][wv4 * 16][0]);    \
    } while (0)

    // prologue: two tiles in flight
    STAGE(0, 0);
    STAGE(1, 1);

#pragma unroll
    for (int it = 0; it < 6; ++it) {
        const int cur = it & 1;
        if (it == 5) { asm volatile("s_waitcnt vmcnt(0)" ::: "memory"); }
        else         { asm volatile("s_waitcnt vmcnt(4)" ::: "memory"); }
        __builtin_amdgcn_s_barrier();          // all waves' stage(it) landed
        __builtin_amdgcn_sched_barrier(0);     // no ds_read hoists above this
#pragma unroll
        for (int ks = 0; ks < 2; ++ks) {
            bf16x8 a = *reinterpret_cast<const bf16x8*>(&Ald[kg][cur][ks][ra][qsw]);
#pragma unroll
            for (int u = 0; u < 4; ++u) {
                bf16x8 w = *reinterpret_cast<const bf16x8*>(
                    &Wld[kg][cur][ks][u * 16 + l16][qsw]);
                acc[u] = __builtin_amdgcn_mfma_f32_16x16x32_bf16(a, w, acc[u], 0, 0, 0);
            }
        }
        __builtin_amdgcn_sched_barrier(0);     // no ds_read sinks below this
        __builtin_amdgcn_s_barrier();          // all reads of buf 'cur' retired
        if (it + 2 < 6) STAGE(it + 2, cur);    // overwrite just-freed buffer
    }
#undef STAGE

    // ---- cross-group reduction through LDS (reuse Ald region: 64x68 f32) ----
    __syncthreads();
    float* Red = reinterpret_cast<float*>(&Ald[0][0][0][0][0]);   // 17.4 KB < 32 KB
    if (kg == 1) {
#pragma unroll
        for (int u = 0; u < 4; ++u)
#pragma unroll
            for (int r = 0; r < 4; ++r)
                Red[(wv4 * 16 + quad * 4 + r) * 68 + u * 16 + l16] = acc[u][r];
    }
    __syncthreads();
    if (kg == 1) return;
#pragma unroll
    for (int u = 0; u < 4; ++u)
#pragma unroll
        for (int r = 0; r < 4; ++r)
            acc[u][r] += Red[(wv4 * 16 + quad * 4 + r) * 68 + u * 16 + l16];

    // ---- epilogue (kg0 only): D row = wv4*16+quad*4+r, col = n0+u*16+l16 ----
    if (ROPE) {
#pragma unroll
        for (int r = 0; r < 4; ++r) {
            int m = m0 + wv4 * 16 + quad * 4 + r;
            int s = m & (S_ - 1);
#pragma unroll
            for (int u = 0; u < 2; ++u) {
                float2 cssn = tab[s * 32 + u * 16 + l16];
                float cs = cssn.x, sn = cssn.y;
                float q0 = acc[u][r];
                float q1 = acc[u + 2][r];
                size_t base = (size_t)m * HID_ + n0 + u * 16 + l16;
                C [base]      = __float2bfloat16(q0);
                C [base + 32] = __float2bfloat16(q1);
                C2[base]      = __float2bfloat16(q0 * cs - q1 * sn);
                C2[base + 32] = __float2bfloat16(q1 * cs + q0 * sn);
            }
        }
    } else {
#pragma unroll
        for (int u = 0; u < 4; ++u)
#pragma unroll
            for (int r = 0; r < 4; ++r) {
                int row = m0 + wv4 * 16 + quad * 4 + r;
                int col = n0 + u * 16 + l16;
                Cf[(size_t)row * N + col] = acc[u][r];
            }
    }
}

// ---------------------------------------------------------------------------
// Banded attention v2: K^T staged in LDS (glds, pre-swizzled source) instead
// of 20 scattered 16B global gathers per wave; Kr union'd with Pl (K dead
// once scores exist) so LDS stays 59 KB -> 2 blocks/CU.  setprio around MFMA
// clusters (2 co-resident blocks at different phases = role-split regime).
//
// Kr layout: [224 rows][64 dims] bf16, linear in LDS.  16B granule g_phys of
// row r holds logical granule g_phys ^ (r&7)  (source pre-swizzled; glds dest
// linear).  Read for (ks,quad): g_phys = (ks*4+quad) ^ (w&7) -> every bank
// gets exactly 8 words per b128 wave-read = the 8-cycle data floor.
// ---------------------------------------------------------------------------
__global__ __launch_bounds__(256) void attn_kernel(
    const __hip_bfloat16* __restrict__ Q,    // pre-rope  (= V)
    const __hip_bfloat16* __restrict__ Qr,   // post-rope (= Q = K)
    __hip_bfloat16* __restrict__ O)
{
    __shared__ __align__(16) __hip_bfloat16 Vt[64][KSTR];   // [dim][window]  29 KB
    __shared__ __align__(16) __hip_bfloat16 KP[64 * KSTR];  // Kr then Pl     29 KB

    const int bh = blockIdx.y;
    const int b  = bh / NH_;
    const int h  = bh % NH_;
    const int i0 = blockIdx.x * 64;
    const int tid = threadIdx.x;

    // ---- stage V^T: one key row per lane (banks = tid/2 -> 2-way = free) ----
    if (tid < KW) {
        int j  = i0 - 64 + tid;
        int jc = min(max(j, 0), S_ - 1);
        const __hip_bfloat16* vrow = Q + ((size_t)(b * S_ + jc)) * HID_ + h * HD_;
#pragma unroll
        for (int d8i = 0; d8i < 8; ++d8i) {
            bf16x8 v = *reinterpret_cast<const bf16x8*>(vrow + d8i * 8);
            const __hip_bfloat16* ve = reinterpret_cast<const __hip_bfloat16*>(&v);
#pragma unroll
            for (int e = 0; e < 8; ++e) Vt[d8i * 8 + e][tid] = ve[e];
        }
    }

    // ---- stage Kr (224x64 bf16 = 28 KB) via glds, source pre-swizzled ----
    {
        const int wvb = (tid >> 6) * 64;              // wave's lane-block base
        const int ln  = tid & 63;
#pragma unroll
        for (int i = 0; i < 7; ++i) {
            int cbase = i * 256 + wvb;                // wave-uniform chunk base
            int cc  = cbase + ln;                     // this lane's 16B chunk
            int row = cc >> 3;
            int gp  = cc & 7;
            int gl  = gp ^ (row & 7);                 // logical granule at src
            int j   = i0 - 64 + row;
            int jc  = min(max(j, 0), S_ - 1);
            gload_lds16(Qr + ((size_t)(b * S_ + jc)) * HID_ + h * HD_ + gl * 8,
                        KP + (size_t)cbase * 8);
        }
    }
    __syncthreads();

    const int wv   = tid >> 6;
    const int lane = tid & 63;
    const int l16  = lane & 15;
    const int quad = lane >> 4;

    // ---- QK^T over the 10 tiles intersecting this wave's band (B from LDS) ----
    floatx4 sc[10] = {};
    const __hip_bfloat16* qrow =
        Qr + ((size_t)(b * S_ + i0 + wv * 16 + l16)) * HID_ + h * HD_ + quad * 8;
    __builtin_amdgcn_s_setprio(1);
#pragma unroll
    for (int ks = 0; ks < 2; ++ks) {
        bf16x8 a = *reinterpret_cast<const bf16x8*>(qrow + ks * 32);
#pragma unroll
        for (int t = 0; t < 10; ++t) {
            int w  = (wv + t) * 16 + l16;
            int gp = ((ks * 4 + quad) ^ (w & 7)) * 8;
            bf16x8 bfr = *reinterpret_cast<const bf16x8*>(&KP[w * 64 + gp]);
            sc[t] = __builtin_amdgcn_mfma_f32_16x16x32_bf16(a, bfr, sc[t], 0, 0, 0);
        }
    }
    __builtin_amdgcn_s_setprio(0);
    __syncthreads();                       // all Kr reads done; KP becomes Pl

    // ---- masked softmax per row ----
    const float scale = 0.125f;
    float denom[4];
#pragma unroll
    for (int r = 0; r < 4; ++r) {
        const int R = wv * 16 + quad * 4 + r;
        float xv[10];
        float mx = -3.0e38f;
#pragma unroll
        for (int t = 0; t < 10; ++t) {
            int w = (wv + t) * 16 + l16;
            int j = i0 - 64 + w;
            bool valid = (w >= R) && (w <= R + 128) && (j >= 0) && (j < S_);
            float x = valid ? sc[t][r] * scale : -1.0e30f;
            xv[t] = x;
            mx = fmaxf(mx, x);
        }
#pragma unroll
        for (int msk = 1; msk < 16; msk <<= 1) mx = fmaxf(mx, __shfl_xor(mx, msk, 64));
        float sum = 0.f;
#pragma unroll
        for (int t = 0; t < 10; ++t) {
            float p = __expf(xv[t] - mx);
            sum += p;
            KP[R * KSTR + (wv + t) * 16 + l16] = __float2bfloat16(p);
        }
#pragma unroll
        for (int msk = 1; msk < 16; msk <<= 1) sum += __shfl_xor(sum, msk, 64);
        denom[r] = sum;
    }
    __syncthreads();

    // ---- PV over the wave's 160-wide band ----
    floatx4 oacc[4] = {};
    __builtin_amdgcn_s_setprio(1);
#pragma unroll
    for (int c = 0; c < 5; ++c) {
        const int base = wv * 16 + c * 32;
        bf16x8 a = *reinterpret_cast<const bf16x8*>(
            &KP[(wv * 16 + l16) * KSTR + base + quad * 8]);
#pragma unroll
        for (int u = 0; u < 4; ++u) {
            bf16x8 bfr = *reinterpret_cast<const bf16x8*>(&Vt[u * 16 + l16][base + quad * 8]);
            oacc[u] = __builtin_amdgcn_mfma_f32_16x16x32_bf16(a, bfr, oacc[u], 0, 0, 0);
        }
    }
    __builtin_amdgcn_s_setprio(0);

    // ---- O writeback via LDS repack (reuse KP as f32 [64][68]) ----
    __syncthreads();                       // all Pl/Vt reads done
    float* Of = reinterpret_cast<float*>(&KP[0]);
#pragma unroll
    for (int u = 0; u < 4; ++u)
#pragma unroll
        for (int r = 0; r < 4; ++r)
            Of[(wv * 16 + quad * 4 + r) * 68 + u * 16 + l16] = oacc[u][r] / denom[r];
    __syncthreads();
    {
        int row = tid >> 2;
        int seg = (tid & 3) * 16;
        __hip_bfloat16 ob[16];
#pragma unroll
        for (int e = 0; e < 16; ++e)
            ob[e] = __float2bfloat16(Of[row * 68 + seg + e]);
        __hip_bfloat16* dst = O + ((size_t)(b * S_ + i0 + row)) * HID_ + h * HD_ + seg;
        *reinterpret_cast<bf16x8*>(dst)     = *reinterpret_cast<bf16x8*>(ob);
        *reinterpret_cast<bf16x8*>(dst + 8) = *reinterpret_cast<bf16x8*>(ob + 8);
    }
}

// ---------------------------------------------------------------------------
extern "C" void kernel_launch(void* const* d_in, const int* in_sizes, int n_in,
                              void* d_out, int out_size, void* d_ws, size_t ws_size,
                              hipStream_t stream)
{
    int ih = -1, iw1 = -1, iw2 = -1, ip = -1;
    for (int i = 0; i < n_in; ++i) {
        int s = in_sizes[i];
        if      (s == N_HID_ELEM && ih < 0) ih = i;
        else if (s == N_W_ELEM)  { if (iw1 < 0) iw1 = i; else if (iw2 < 0) iw2 = i; }
        else if (s == S_ && ip < 0) ip = i;
    }
    if (ih < 0)  ih = 0;
    if (iw1 < 0) iw1 = 1;
    if (iw2 < 0) iw2 = 2;
    if (ip < 0)  ip = 5;

    const float* hidden = (const float*)d_in[ih];
    const float* w1     = (const float*)d_in[iw1];
    const float* w2     = (const float*)d_in[iw2];
    const int*   pos    = (const int*)d_in[ip];

    __hip_bfloat16* Hb  = (__hip_bfloat16*)d_ws;
    __hip_bfloat16* Wqb = Hb  + N_HID_ELEM;
    __hip_bfloat16* Wob = Wqb + N_W_ELEM;
    __hip_bfloat16* Q   = Wob + N_W_ELEM;
    __hip_bfloat16* Qr  = Q   + N_HID_ELEM;
    float2*         Tab = reinterpret_cast<float2*>(Qr + N_HID_ELEM);  // 512 KB
    __hip_bfloat16* AO  = Hb;   // Hb dead after gemm1

    int conv4 = (N_HID_ELEM + 2 * N_W_ELEM) / 4;
    int convtot = conv4 + TAB_ELEMS;
    convert_inputs_kernel<<<(convtot + 255) / 256, 256, 0, stream>>>(
        hidden, w1, w2, pos, Hb, Wqb, Wob, Tab);

    dim3 gblk(NROWS / 64, HID_ / 64);   // (64, 12) = 768 blocks

    // GEMM1 + fused RoPE -> Q, Qr
    gemm64k2<1><<<gblk, 512, 0, stream>>>(Hb, Wqb, Q, Qr, nullptr, Tab,
                                          NROWS, HID_, HID_);

    attn_kernel<<<dim3(S_ / 64, B_ * NH_), 256, 0, stream>>>(Q, Qr, AO);

    // GEMM2 -> fp32 out
    gemm64k2<0><<<gblk, 512, 0, stream>>>(AO, Wob, nullptr, nullptr, (float*)d_out,
                                          nullptr, NROWS, HID_, HID_);
}